// Round 6
// baseline (315.153 us; speedup 1.0000x reference)
//
#include <hip/hip_runtime.h>

#define HW    128
#define CDIM  128
#define BDIM  32
#define NPIX  (HW * HW)      // 16384
#define N1    (HW - 1)       // 127
#define SLABS 64             // slabs per batch in k1; 256 pixels per slab
#define NBLK1 (BDIM * SLABS) // 2048 k1 blocks

typedef float vfloat4 __attribute__((ext_vector_type(4)));

__device__ __forceinline__ float4 nt_load4(const float4* p) {
    vfloat4 t = __builtin_nontemporal_load((const vfloat4*)p);
    return make_float4(t.x, t.y, t.z, t.w);
}
__device__ __forceinline__ void nt_store4(float4* p, float4 v) {
    vfloat4 t; t.x = v.x; t.y = v.y; t.z = v.z; t.w = v.w;
    __builtin_nontemporal_store(t, (vfloat4*)p);
}

// ---------------------------------------------------------------------------
// Kernel 1: per-block partial selector logits + last-block finalize (softmax).
// grid = 2048 (32 b * 64 slabs), block = 256.
// The 2048th block to finish reduces all partials and writes wts[32][4],
// eliminating the separate k2 dispatch and its launch gap.
// ---------------------------------------------------------------------------
__global__ __launch_bounds__(256) void k1_partial(
    const float* __restrict__ x,
    const float* __restrict__ Wsel,
    const float* __restrict__ bsel,
    float* __restrict__ partial,
    float* __restrict__ wts,
    unsigned* __restrict__ cnt) {
    int blk  = blockIdx.x;        // 0..2047
    int b    = blk >> 6;          // 0..31
    int slab = blk & 63;          // 0..63
    int tid  = threadIdx.x;       // 0..255
    int c4   = tid & 31;          // float4 index within a C-row
    int po   = tid >> 5;          // 0..7 pixel offset

    const float4* xb = (const float4*)(x + (size_t)b * NPIX * CDIM);
    float4 acc = make_float4(0.f, 0.f, 0.f, 0.f);
    int pixbase = slab * 256 + po;
    #pragma unroll 4
    for (int k = 0; k < 32; ++k) {
        int pix = pixbase + k * 8;
        float4 v = nt_load4(&xb[(size_t)pix * 32 + c4]);
        acc.x += v.x; acc.y += v.y; acc.z += v.z; acc.w += v.w;
    }

    // logit contribution: lg[i] = sum_j acc[j] * W_sel[c4*4+j][i]
    const float4* W4 = (const float4*)Wsel;   // W4[c] = W_sel[c][0..3]
    float4 w0 = W4[c4 * 4 + 0];
    float4 w1 = W4[c4 * 4 + 1];
    float4 w2 = W4[c4 * 4 + 2];
    float4 w3 = W4[c4 * 4 + 3];
    float4 lg;
    lg.x = acc.x * w0.x + acc.y * w1.x + acc.z * w2.x + acc.w * w3.x;
    lg.y = acc.x * w0.y + acc.y * w1.y + acc.z * w2.y + acc.w * w3.y;
    lg.z = acc.x * w0.z + acc.y * w1.z + acc.z * w2.z + acc.w * w3.z;
    lg.w = acc.x * w0.w + acc.y * w1.w + acc.z * w2.w + acc.w * w3.w;

    __shared__ float4 s[256];
    __shared__ int isLast;
    s[tid] = lg;
    __syncthreads();
    #pragma unroll
    for (int off = 128; off > 0; off >>= 1) {
        if (tid < off) {
            float4 a = s[tid], c = s[tid + off];
            a.x += c.x; a.y += c.y; a.z += c.z; a.w += c.w;
            s[tid] = a;
        }
        __syncthreads();
    }
    if (tid == 0) {
        ((float4*)partial)[blk] = s[0];
        __threadfence();   // make partial visible at agent scope before ticket
        unsigned old = __hip_atomic_fetch_add(cnt, 1u, __ATOMIC_ACQ_REL,
                                              __HIP_MEMORY_SCOPE_AGENT);
        isLast = (old == NBLK1 - 1) ? 1 : 0;
    }
    __syncthreads();

    if (isLast) {
        // Finalize: thread t handles (batch bb = t>>3, group g = t&7),
        // summing 8 slabs, then an 8-lane shfl reduce, then softmax at g==0.
        int bb = tid >> 3;        // 0..31
        int g  = tid & 7;         // 0..7
        float4 v = make_float4(0.f, 0.f, 0.f, 0.f);
        #pragma unroll
        for (int k = 0; k < 8; ++k) {
            int idx = (bb * 64 + g * 8 + k) * 4;
            // agent-scope atomic loads: coherent view of other XCDs' writes
            v.x += __hip_atomic_load(&partial[idx + 0], __ATOMIC_RELAXED, __HIP_MEMORY_SCOPE_AGENT);
            v.y += __hip_atomic_load(&partial[idx + 1], __ATOMIC_RELAXED, __HIP_MEMORY_SCOPE_AGENT);
            v.z += __hip_atomic_load(&partial[idx + 2], __ATOMIC_RELAXED, __HIP_MEMORY_SCOPE_AGENT);
            v.w += __hip_atomic_load(&partial[idx + 3], __ATOMIC_RELAXED, __HIP_MEMORY_SCOPE_AGENT);
        }
        #pragma unroll
        for (int off = 4; off > 0; off >>= 1) {
            v.x += __shfl_down(v.x, off, 8);
            v.y += __shfl_down(v.y, off, 8);
            v.z += __shfl_down(v.z, off, 8);
            v.w += __shfl_down(v.w, off, 8);
        }
        if (g == 0) {
            const float inv = 1.0f / (float)NPIX;
            float l0 = v.x * inv + bsel[0];
            float l1 = v.y * inv + bsel[1];
            float l2 = v.z * inv + bsel[2];
            float l3 = v.w * inv + bsel[3];
            float m  = fmaxf(fmaxf(l0, l1), fmaxf(l2, l3));
            float e0 = expf(l0 - m), e1 = expf(l1 - m);
            float e2 = expf(l2 - m), e3 = expf(l3 - m);
            float is = 1.0f / (e0 + e1 + e2 + e3);
            wts[bb * 4 + 0] = e0 * is;
            wts[bb * 4 + 1] = e1 * is;
            wts[bb * 4 + 2] = e2 * is;
            wts[bb * 4 + 3] = e3 * is;
        }
    }
}

// ---------------------------------------------------------------------------
// Kernel 2 (was k3): weighted rotation sum via 4-orbits.
// One thread reads 4 rotated float4s (nt) and writes 4 (nt): x read once,
// out written once. grid = 32 b * 512 groups, block = 256.
// ---------------------------------------------------------------------------
__device__ __forceinline__ float4 comb(float s0, float s1, float s2, float s3,
                                       float4 a, float4 b, float4 c, float4 d) {
    float4 r;
    r.x = s0 * a.x + s1 * b.x + s2 * c.x + s3 * d.x;
    r.y = s0 * a.y + s1 * b.y + s2 * c.y + s3 * d.y;
    r.z = s0 * a.z + s1 * b.z + s2 * c.z + s3 * d.z;
    r.w = s0 * a.w + s1 * b.w + s2 * c.w + s3 * d.w;
    return r;
}

__global__ __launch_bounds__(256) void k3_rot(
    const float* __restrict__ x,
    const float* __restrict__ wts,
    float* __restrict__ out) {
    int blk = blockIdx.x;           // 0..16383
    int b   = blk >> 9;             // 0..31
    int grp = blk & 511;            // 0..511
    int tid = threadIdx.x;
    int c4  = tid & 31;             // float4 index within C-row
    int o   = tid >> 5;             // 0..7
    int orbit = grp * 8 + o;        // 0..4095
    int h = orbit >> 6;             // 0..63
    int w = orbit & 63;             // 0..63

    float4 sv = *(const float4*)(wts + b * 4);
    float s0 = sv.x, s1 = sv.y, s2 = sv.z, s3 = sv.w;

    const float4* xb = (const float4*)(x + (size_t)b * NPIX * CDIM);
    float4*       ob = (float4*)(out + (size_t)b * NPIX * CDIM);

    int p0 = (h * HW + w) * 32 + c4;
    int p1 = (w * HW + (N1 - h)) * 32 + c4;
    int p2 = ((N1 - h) * HW + (N1 - w)) * 32 + c4;
    int p3 = ((N1 - w) * HW + h) * 32 + c4;

    float4 a0 = nt_load4(&xb[p0]);
    float4 a1 = nt_load4(&xb[p1]);
    float4 a2 = nt_load4(&xb[p2]);
    float4 a3 = nt_load4(&xb[p3]);

    // out[p_k] = s0*x[p_k] + s1*x[p_{k+1}] + s2*x[p_{k+2}] + s3*x[p_{k+3}]
    nt_store4(&ob[p0], comb(s0, s1, s2, s3, a0, a1, a2, a3));
    nt_store4(&ob[p1], comb(s0, s1, s2, s3, a1, a2, a3, a0));
    nt_store4(&ob[p2], comb(s0, s1, s2, s3, a2, a3, a0, a1));
    nt_store4(&ob[p3], comb(s0, s1, s2, s3, a3, a0, a1, a2));
}

extern "C" void kernel_launch(void* const* d_in, const int* in_sizes, int n_in,
                              void* d_out, int out_size, void* d_ws, size_t ws_size,
                              hipStream_t stream) {
    const float* x    = (const float*)d_in[0];
    const float* Wsel = (const float*)d_in[1];
    const float* bsel = (const float*)d_in[2];
    float* out = (float*)d_out;

    float*    partial = (float*)d_ws;                         // 2048*4 floats
    float*    wts     = (float*)((char*)d_ws + 2048 * 4 * sizeof(float));
    unsigned* cnt     = (unsigned*)((char*)d_ws + 2112 * 4 * sizeof(float));

    hipMemsetAsync(cnt, 0, sizeof(unsigned), stream);
    k1_partial<<<NBLK1, 256, 0, stream>>>(x, Wsel, bsel, partial, wts, cnt);
    k3_rot<<<BDIM * 512, 256, 0, stream>>>(x, wts, out);
}

// Round 7
// 177.242 us; speedup vs baseline: 1.7781x; 1.7781x over previous
//
#include <hip/hip_runtime.h>

#define HW    128
#define CDIM  128
#define BDIM  32
#define NPIX  (HW * HW)      // 16384
#define N1    (HW - 1)       // 127
#define SLABS 64             // slabs per batch in k1; 256 pixels per slab

typedef float vfloat4 __attribute__((ext_vector_type(4)));

__device__ __forceinline__ void nt_store4(float4* p, float4 v) {
    vfloat4 t; t.x = v.x; t.y = v.y; t.z = v.z; t.w = v.w;
    __builtin_nontemporal_store(t, (vfloat4*)p);
}

// ---------------------------------------------------------------------------
// Kernel 1: per-block partial selector logits, with per-BATCH last-block
// finalize (softmax). grid = 2048 (32 b * 64 slabs), block = 256.
// Ticket discipline (R6 lesson): 64 release-RMWs per counter line, 32 lines —
// NOT 2048 acq_rel RMWs on one line (that cost ~180 us of serialization).
// Reads are normal (cached) float4 loads — R2-proven ~6.4 TB/s.
// ---------------------------------------------------------------------------
__global__ __launch_bounds__(256) void k1_partial(
    const float* __restrict__ x,
    const float* __restrict__ Wsel,
    const float* __restrict__ bsel,
    float* __restrict__ partial,
    float* __restrict__ wts,
    unsigned* __restrict__ cnt) {
    int blk  = blockIdx.x;        // 0..2047
    int b    = blk >> 6;          // 0..31
    int slab = blk & 63;          // 0..63
    int tid  = threadIdx.x;       // 0..255
    int c4   = tid & 31;          // float4 index within a C-row
    int po   = tid >> 5;          // 0..7 pixel offset

    const float4* xb = (const float4*)(x + (size_t)b * NPIX * CDIM);
    float4 acc = make_float4(0.f, 0.f, 0.f, 0.f);
    int pixbase = slab * 256 + po;
    #pragma unroll 4
    for (int k = 0; k < 32; ++k) {
        int pix = pixbase + k * 8;
        float4 v = xb[(size_t)pix * 32 + c4];
        acc.x += v.x; acc.y += v.y; acc.z += v.z; acc.w += v.w;
    }

    // logit contribution: lg[i] = sum_j acc[j] * W_sel[c4*4+j][i]
    const float4* W4 = (const float4*)Wsel;   // W4[c] = W_sel[c][0..3]
    float4 w0 = W4[c4 * 4 + 0];
    float4 w1 = W4[c4 * 4 + 1];
    float4 w2 = W4[c4 * 4 + 2];
    float4 w3 = W4[c4 * 4 + 3];
    float4 lg;
    lg.x = acc.x * w0.x + acc.y * w1.x + acc.z * w2.x + acc.w * w3.x;
    lg.y = acc.x * w0.y + acc.y * w1.y + acc.z * w2.y + acc.w * w3.y;
    lg.z = acc.x * w0.z + acc.y * w1.z + acc.z * w2.z + acc.w * w3.z;
    lg.w = acc.x * w0.w + acc.y * w1.w + acc.z * w2.w + acc.w * w3.w;

    __shared__ float4 s[256];
    __shared__ unsigned old_s;
    s[tid] = lg;
    __syncthreads();
    #pragma unroll
    for (int off = 128; off > 0; off >>= 1) {
        if (tid < off) {
            float4 a = s[tid], c = s[tid + off];
            a.x += c.x; a.y += c.y; a.z += c.z; a.w += c.w;
            s[tid] = a;
        }
        __syncthreads();
    }
    if (tid == 0) {
        ((float4*)partial)[blk] = s[0];
        // RELEASE orders the partial store before the count at agent scope.
        old_s = __hip_atomic_fetch_add(&cnt[b], 1u, __ATOMIC_RELEASE,
                                       __HIP_MEMORY_SCOPE_AGENT);
    }
    __syncthreads();

    if (old_s == SLABS - 1 && tid < 64) {
        // Last block of this batch: acquire the release sequence, then
        // reduce this batch's 64 partials and write the softmax weights.
        (void)__hip_atomic_load(&cnt[b], __ATOMIC_ACQUIRE,
                                __HIP_MEMORY_SCOPE_AGENT);
        int idx = (b * 64 + tid) * 4;
        float4 v;
        v.x = __hip_atomic_load(&partial[idx + 0], __ATOMIC_RELAXED, __HIP_MEMORY_SCOPE_AGENT);
        v.y = __hip_atomic_load(&partial[idx + 1], __ATOMIC_RELAXED, __HIP_MEMORY_SCOPE_AGENT);
        v.z = __hip_atomic_load(&partial[idx + 2], __ATOMIC_RELAXED, __HIP_MEMORY_SCOPE_AGENT);
        v.w = __hip_atomic_load(&partial[idx + 3], __ATOMIC_RELAXED, __HIP_MEMORY_SCOPE_AGENT);
        #pragma unroll
        for (int off = 32; off > 0; off >>= 1) {
            v.x += __shfl_down(v.x, off, 64);
            v.y += __shfl_down(v.y, off, 64);
            v.z += __shfl_down(v.z, off, 64);
            v.w += __shfl_down(v.w, off, 64);
        }
        if (tid == 0) {
            const float inv = 1.0f / (float)NPIX;
            float l0 = v.x * inv + bsel[0];
            float l1 = v.y * inv + bsel[1];
            float l2 = v.z * inv + bsel[2];
            float l3 = v.w * inv + bsel[3];
            float m  = fmaxf(fmaxf(l0, l1), fmaxf(l2, l3));
            float e0 = expf(l0 - m), e1 = expf(l1 - m);
            float e2 = expf(l2 - m), e3 = expf(l3 - m);
            float is = 1.0f / (e0 + e1 + e2 + e3);
            wts[b * 4 + 0] = e0 * is;
            wts[b * 4 + 1] = e1 * is;
            wts[b * 4 + 2] = e2 * is;
            wts[b * 4 + 3] = e3 * is;
        }
    }
}

// ---------------------------------------------------------------------------
// Kernel 2: weighted rotation sum via 4-orbits.
// Normal (cached) reads, nontemporal stores — R2-proven policy (~6.6 TB/s).
// One thread reads 4 rotated float4s and writes 4: x read once, out written
// once. grid = 32 b * 512 groups, block = 256.
// ---------------------------------------------------------------------------
__device__ __forceinline__ float4 comb(float s0, float s1, float s2, float s3,
                                       float4 a, float4 b, float4 c, float4 d) {
    float4 r;
    r.x = s0 * a.x + s1 * b.x + s2 * c.x + s3 * d.x;
    r.y = s0 * a.y + s1 * b.y + s2 * c.y + s3 * d.y;
    r.z = s0 * a.z + s1 * b.z + s2 * c.z + s3 * d.z;
    r.w = s0 * a.w + s1 * b.w + s2 * c.w + s3 * d.w;
    return r;
}

__global__ __launch_bounds__(256) void k3_rot(
    const float* __restrict__ x,
    const float* __restrict__ wts,
    float* __restrict__ out) {
    int blk = blockIdx.x;           // 0..16383
    int b   = blk >> 9;             // 0..31
    int grp = blk & 511;            // 0..511
    int tid = threadIdx.x;
    int c4  = tid & 31;             // float4 index within C-row
    int o   = tid >> 5;             // 0..7
    int orbit = grp * 8 + o;        // 0..4095
    int h = orbit >> 6;             // 0..63
    int w = orbit & 63;             // 0..63

    float4 sv = *(const float4*)(wts + b * 4);
    float s0 = sv.x, s1 = sv.y, s2 = sv.z, s3 = sv.w;

    const float4* xb = (const float4*)(x + (size_t)b * NPIX * CDIM);
    float4*       ob = (float4*)(out + (size_t)b * NPIX * CDIM);

    int p0 = (h * HW + w) * 32 + c4;
    int p1 = (w * HW + (N1 - h)) * 32 + c4;
    int p2 = ((N1 - h) * HW + (N1 - w)) * 32 + c4;
    int p3 = ((N1 - w) * HW + h) * 32 + c4;

    float4 a0 = xb[p0];
    float4 a1 = xb[p1];
    float4 a2 = xb[p2];
    float4 a3 = xb[p3];

    // out[p_k] = s0*x[p_k] + s1*x[p_{k+1}] + s2*x[p_{k+2}] + s3*x[p_{k+3}]
    nt_store4(&ob[p0], comb(s0, s1, s2, s3, a0, a1, a2, a3));
    nt_store4(&ob[p1], comb(s0, s1, s2, s3, a1, a2, a3, a0));
    nt_store4(&ob[p2], comb(s0, s1, s2, s3, a2, a3, a0, a1));
    nt_store4(&ob[p3], comb(s0, s1, s2, s3, a3, a0, a1, a2));
}

extern "C" void kernel_launch(void* const* d_in, const int* in_sizes, int n_in,
                              void* d_out, int out_size, void* d_ws, size_t ws_size,
                              hipStream_t stream) {
    const float* x    = (const float*)d_in[0];
    const float* Wsel = (const float*)d_in[1];
    const float* bsel = (const float*)d_in[2];
    float* out = (float*)d_out;

    float*    partial = (float*)d_ws;                          // 2048*4 floats
    float*    wts     = (float*)((char*)d_ws + 2048 * 4 * sizeof(float));
    unsigned* cnt     = (unsigned*)((char*)d_ws + 2112 * 4 * sizeof(float)); // 32 uints

    hipMemsetAsync(cnt, 0, 32 * sizeof(unsigned), stream);
    k1_partial<<<BDIM * SLABS, 256, 0, stream>>>(x, Wsel, bsel, partial, wts, cnt);
    k3_rot<<<BDIM * 512, 256, 0, stream>>>(x, wts, out);
}

// Round 8
// 176.210 us; speedup vs baseline: 1.7885x; 1.0059x over previous
//
#include <hip/hip_runtime.h>

#define HW    128
#define CDIM  128
#define BDIM  32
#define NPIX  (HW * HW)      // 16384
#define N1    (HW - 1)       // 127
#define SLABS 64             // slabs per batch in k1; 256 pixels per slab
#define CNT_STRIDE 32        // ticket padding: 32 uints = 128 B = 1 cache line

typedef float vfloat4 __attribute__((ext_vector_type(4)));

__device__ __forceinline__ void nt_store4(float4* p, float4 v) {
    vfloat4 t; t.x = v.x; t.y = v.y; t.z = v.z; t.w = v.w;
    __builtin_nontemporal_store(t, (vfloat4*)p);
}

// ---------------------------------------------------------------------------
// Kernel 1: per-block partial selector logits + per-batch last-block softmax.
// grid = 2048 (32 b * 64 slabs), block = 256.
// Ticket discipline (R6/R7 lessons, quantified): a contended same-line
// device-scope RMW costs ~90 ns SERIALIZED. 2048 on 1 line = +180 us (R6);
// on 2 lines = +145 us (R7, false sharing of the 4-B-strided counters).
// Fix: one counter per 128-B cache line -> 64 RMWs/line, 32 lines in
// parallel ~= 6 us, hidden under streaming.
// ---------------------------------------------------------------------------
__global__ __launch_bounds__(256) void k1_partial(
    const float* __restrict__ x,
    const float* __restrict__ Wsel,
    const float* __restrict__ bsel,
    float* __restrict__ partial,
    float* __restrict__ wts,
    unsigned* __restrict__ cnt) {
    int blk  = blockIdx.x;        // 0..2047
    int b    = blk >> 6;          // 0..31
    int slab = blk & 63;          // 0..63
    int tid  = threadIdx.x;       // 0..255
    int c4   = tid & 31;          // float4 index within a C-row
    int po   = tid >> 5;          // 0..7 pixel offset

    const float4* xb = (const float4*)(x + (size_t)b * NPIX * CDIM);
    float4 acc = make_float4(0.f, 0.f, 0.f, 0.f);
    int pixbase = slab * 256 + po;
    #pragma unroll 4
    for (int k = 0; k < 32; ++k) {
        int pix = pixbase + k * 8;
        float4 v = xb[(size_t)pix * 32 + c4];
        acc.x += v.x; acc.y += v.y; acc.z += v.z; acc.w += v.w;
    }

    // logit contribution: lg[i] = sum_j acc[j] * W_sel[c4*4+j][i]
    const float4* W4 = (const float4*)Wsel;   // W4[c] = W_sel[c][0..3]
    float4 w0 = W4[c4 * 4 + 0];
    float4 w1 = W4[c4 * 4 + 1];
    float4 w2 = W4[c4 * 4 + 2];
    float4 w3 = W4[c4 * 4 + 3];
    float4 lg;
    lg.x = acc.x * w0.x + acc.y * w1.x + acc.z * w2.x + acc.w * w3.x;
    lg.y = acc.x * w0.y + acc.y * w1.y + acc.z * w2.y + acc.w * w3.y;
    lg.z = acc.x * w0.z + acc.y * w1.z + acc.z * w2.z + acc.w * w3.z;
    lg.w = acc.x * w0.w + acc.y * w1.w + acc.z * w2.w + acc.w * w3.w;

    __shared__ float4 s[256];
    __shared__ unsigned old_s;
    s[tid] = lg;
    __syncthreads();
    #pragma unroll
    for (int off = 128; off > 0; off >>= 1) {
        if (tid < off) {
            float4 a = s[tid], c = s[tid + off];
            a.x += c.x; a.y += c.y; a.z += c.z; a.w += c.w;
            s[tid] = a;
        }
        __syncthreads();
    }
    if (tid == 0) {
        ((float4*)partial)[blk] = s[0];
        // RELEASE orders the partial store before the count at agent scope.
        old_s = __hip_atomic_fetch_add(&cnt[b * CNT_STRIDE], 1u,
                                       __ATOMIC_RELEASE,
                                       __HIP_MEMORY_SCOPE_AGENT);
    }
    __syncthreads();

    if (old_s == SLABS - 1 && tid < 64) {
        // Last block of this batch: acquire the release sequence, then
        // reduce this batch's 64 partials and write the softmax weights.
        (void)__hip_atomic_load(&cnt[b * CNT_STRIDE], __ATOMIC_ACQUIRE,
                                __HIP_MEMORY_SCOPE_AGENT);
        int idx = (b * 64 + tid) * 4;
        float4 v;
        v.x = __hip_atomic_load(&partial[idx + 0], __ATOMIC_RELAXED, __HIP_MEMORY_SCOPE_AGENT);
        v.y = __hip_atomic_load(&partial[idx + 1], __ATOMIC_RELAXED, __HIP_MEMORY_SCOPE_AGENT);
        v.z = __hip_atomic_load(&partial[idx + 2], __ATOMIC_RELAXED, __HIP_MEMORY_SCOPE_AGENT);
        v.w = __hip_atomic_load(&partial[idx + 3], __ATOMIC_RELAXED, __HIP_MEMORY_SCOPE_AGENT);
        #pragma unroll
        for (int off = 32; off > 0; off >>= 1) {
            v.x += __shfl_down(v.x, off, 64);
            v.y += __shfl_down(v.y, off, 64);
            v.z += __shfl_down(v.z, off, 64);
            v.w += __shfl_down(v.w, off, 64);
        }
        if (tid == 0) {
            const float inv = 1.0f / (float)NPIX;
            float l0 = v.x * inv + bsel[0];
            float l1 = v.y * inv + bsel[1];
            float l2 = v.z * inv + bsel[2];
            float l3 = v.w * inv + bsel[3];
            float m  = fmaxf(fmaxf(l0, l1), fmaxf(l2, l3));
            float e0 = expf(l0 - m), e1 = expf(l1 - m);
            float e2 = expf(l2 - m), e3 = expf(l3 - m);
            float is = 1.0f / (e0 + e1 + e2 + e3);
            wts[b * 4 + 0] = e0 * is;
            wts[b * 4 + 1] = e1 * is;
            wts[b * 4 + 2] = e2 * is;
            wts[b * 4 + 3] = e3 * is;
        }
    }
}

// ---------------------------------------------------------------------------
// Kernel 2: weighted rotation sum via 4-orbits.
// Normal (cached) reads, nontemporal stores — R2-proven policy (~6.6 TB/s).
// One thread reads 4 rotated float4s and writes 4: x read once, out written
// once. grid = 32 b * 512 groups, block = 256.
// ---------------------------------------------------------------------------
__device__ __forceinline__ float4 comb(float s0, float s1, float s2, float s3,
                                       float4 a, float4 b, float4 c, float4 d) {
    float4 r;
    r.x = s0 * a.x + s1 * b.x + s2 * c.x + s3 * d.x;
    r.y = s0 * a.y + s1 * b.y + s2 * c.y + s3 * d.y;
    r.z = s0 * a.z + s1 * b.z + s2 * c.z + s3 * d.z;
    r.w = s0 * a.w + s1 * b.w + s2 * c.w + s3 * d.w;
    return r;
}

__global__ __launch_bounds__(256) void k3_rot(
    const float* __restrict__ x,
    const float* __restrict__ wts,
    float* __restrict__ out) {
    int blk = blockIdx.x;           // 0..16383
    int b   = blk >> 9;             // 0..31
    int grp = blk & 511;            // 0..511
    int tid = threadIdx.x;
    int c4  = tid & 31;             // float4 index within C-row
    int o   = tid >> 5;             // 0..7
    int orbit = grp * 8 + o;        // 0..4095
    int h = orbit >> 6;             // 0..63
    int w = orbit & 63;             // 0..63

    float4 sv = *(const float4*)(wts + b * 4);
    float s0 = sv.x, s1 = sv.y, s2 = sv.z, s3 = sv.w;

    const float4* xb = (const float4*)(x + (size_t)b * NPIX * CDIM);
    float4*       ob = (float4*)(out + (size_t)b * NPIX * CDIM);

    int p0 = (h * HW + w) * 32 + c4;
    int p1 = (w * HW + (N1 - h)) * 32 + c4;
    int p2 = ((N1 - h) * HW + (N1 - w)) * 32 + c4;
    int p3 = ((N1 - w) * HW + h) * 32 + c4;

    float4 a0 = xb[p0];
    float4 a1 = xb[p1];
    float4 a2 = xb[p2];
    float4 a3 = xb[p3];

    // out[p_k] = s0*x[p_k] + s1*x[p_{k+1}] + s2*x[p_{k+2}] + s3*x[p_{k+3}]
    nt_store4(&ob[p0], comb(s0, s1, s2, s3, a0, a1, a2, a3));
    nt_store4(&ob[p1], comb(s0, s1, s2, s3, a1, a2, a3, a0));
    nt_store4(&ob[p2], comb(s0, s1, s2, s3, a2, a3, a0, a1));
    nt_store4(&ob[p3], comb(s0, s1, s2, s3, a3, a0, a1, a2));
}

extern "C" void kernel_launch(void* const* d_in, const int* in_sizes, int n_in,
                              void* d_out, int out_size, void* d_ws, size_t ws_size,
                              hipStream_t stream) {
    const float* x    = (const float*)d_in[0];
    const float* Wsel = (const float*)d_in[1];
    const float* bsel = (const float*)d_in[2];
    float* out = (float*)d_out;

    float*    partial = (float*)d_ws;                          // 2048*4 floats
    float*    wts     = (float*)((char*)d_ws + 2048 * 4 * sizeof(float));
    unsigned* cnt     = (unsigned*)((char*)d_ws + 2112 * 4 * sizeof(float)); // 32 padded lines

    hipMemsetAsync(cnt, 0, BDIM * CNT_STRIDE * sizeof(unsigned), stream);
    k1_partial<<<BDIM * SLABS, 256, 0, stream>>>(x, Wsel, bsel, partial, wts, cnt);
    k3_rot<<<BDIM * 512, 256, 0, stream>>>(x, wts, out);
}

// Round 9
// 122.206 us; speedup vs baseline: 2.5789x; 1.4419x over previous
//
#include <hip/hip_runtime.h>

#define HW    128
#define CDIM  128
#define BDIM  32
#define NPIX  (HW * HW)      // 16384
#define N1    (HW - 1)       // 127
#define SLABS 64             // slabs per batch in k1; 256 pixels per slab

typedef float vfloat4 __attribute__((ext_vector_type(4)));

__device__ __forceinline__ void nt_store4(float4* p, float4 v) {
    vfloat4 t; t.x = v.x; t.y = v.y; t.z = v.z; t.w = v.w;
    __builtin_nontemporal_store(t, (vfloat4*)p);
}

// ---------------------------------------------------------------------------
// Kernel 1: per-block partial selector logits. Pure streaming, NO atomics.
// (R6/R7/R8 lesson: one agent-scope release RMW per block costs ~90 ns
// SERIALIZED device-wide -> +145..185 us on a 2048-block kernel, independent
// of counter layout. Cross-kernel ordering via the dispatch boundary is free.)
// grid = 2048 (32 b * 64 slabs), block = 256.
// ---------------------------------------------------------------------------
__global__ __launch_bounds__(256) void k1_partial(
    const float* __restrict__ x,
    const float* __restrict__ Wsel,
    float* __restrict__ partial) {
    int blk  = blockIdx.x;        // 0..2047
    int b    = blk >> 6;          // 0..31
    int slab = blk & 63;          // 0..63
    int tid  = threadIdx.x;       // 0..255
    int c4   = tid & 31;          // float4 index within a C-row
    int po   = tid >> 5;          // 0..7 pixel offset

    const float4* xb = (const float4*)(x + (size_t)b * NPIX * CDIM);
    float4 acc = make_float4(0.f, 0.f, 0.f, 0.f);
    int pixbase = slab * 256 + po;
    #pragma unroll 4
    for (int k = 0; k < 32; ++k) {
        int pix = pixbase + k * 8;
        float4 v = xb[(size_t)pix * 32 + c4];
        acc.x += v.x; acc.y += v.y; acc.z += v.z; acc.w += v.w;
    }

    // logit contribution: lg[i] = sum_j acc[j] * W_sel[c4*4+j][i]
    const float4* W4 = (const float4*)Wsel;   // W4[c] = W_sel[c][0..3]
    float4 w0 = W4[c4 * 4 + 0];
    float4 w1 = W4[c4 * 4 + 1];
    float4 w2 = W4[c4 * 4 + 2];
    float4 w3 = W4[c4 * 4 + 3];
    float4 lg;
    lg.x = acc.x * w0.x + acc.y * w1.x + acc.z * w2.x + acc.w * w3.x;
    lg.y = acc.x * w0.y + acc.y * w1.y + acc.z * w2.y + acc.w * w3.y;
    lg.z = acc.x * w0.z + acc.y * w1.z + acc.z * w2.z + acc.w * w3.z;
    lg.w = acc.x * w0.w + acc.y * w1.w + acc.z * w2.w + acc.w * w3.w;

    __shared__ float4 s[256];
    s[tid] = lg;
    __syncthreads();
    #pragma unroll
    for (int off = 128; off > 0; off >>= 1) {
        if (tid < off) {
            float4 a = s[tid], c = s[tid + off];
            a.x += c.x; a.y += c.y; a.z += c.z; a.w += c.w;
            s[tid] = a;
        }
        __syncthreads();
    }
    if (tid == 0) ((float4*)partial)[blk] = s[0];
}

// ---------------------------------------------------------------------------
// Kernel 2: weighted rotation sum via 4-orbits, with the selector softmax
// computed redundantly in each block's prologue (replaces the k2 dispatch).
// Order matters: the 4 x-loads are issued FIRST (they don't depend on the
// weights), so the 1 KB partial-reduce + softmax in wave 0 hides under the
// x-load latency. Normal reads + nontemporal stores (R2-proven ~6.6 TB/s).
// grid = 32 b * 512 groups, block = 256.
// ---------------------------------------------------------------------------
__device__ __forceinline__ float4 comb(float s0, float s1, float s2, float s3,
                                       float4 a, float4 b, float4 c, float4 d) {
    float4 r;
    r.x = s0 * a.x + s1 * b.x + s2 * c.x + s3 * d.x;
    r.y = s0 * a.y + s1 * b.y + s2 * c.y + s3 * d.y;
    r.z = s0 * a.z + s1 * b.z + s2 * c.z + s3 * d.z;
    r.w = s0 * a.w + s1 * b.w + s2 * c.w + s3 * d.w;
    return r;
}

__global__ __launch_bounds__(256) void k3_rot(
    const float* __restrict__ x,
    const float* __restrict__ partial,
    const float* __restrict__ bsel,
    float* __restrict__ out) {
    int blk = blockIdx.x;           // 0..16383
    int b   = blk >> 9;             // 0..31
    int grp = blk & 511;            // 0..511
    int tid = threadIdx.x;
    int c4  = tid & 31;             // float4 index within C-row
    int o   = tid >> 5;             // 0..7
    int orbit = grp * 8 + o;        // 0..4095
    int h = orbit >> 6;             // 0..63
    int w = orbit & 63;             // 0..63

    const float4* xb = (const float4*)(x + (size_t)b * NPIX * CDIM);
    float4*       ob = (float4*)(out + (size_t)b * NPIX * CDIM);

    int p0 = (h * HW + w) * 32 + c4;
    int p1 = (w * HW + (N1 - h)) * 32 + c4;
    int p2 = ((N1 - h) * HW + (N1 - w)) * 32 + c4;
    int p3 = ((N1 - w) * HW + h) * 32 + c4;

    // Issue the big loads first; their latency covers the softmax below.
    float4 a0 = xb[p0];
    float4 a1 = xb[p1];
    float4 a2 = xb[p2];
    float4 a3 = xb[p3];

    // Wave 0: reduce this batch's 64 partials, softmax -> LDS broadcast.
    __shared__ float wts_s[4];
    if (tid < 64) {
        float4 v = ((const float4*)partial)[b * 64 + tid];
        #pragma unroll
        for (int off = 32; off > 0; off >>= 1) {
            v.x += __shfl_down(v.x, off, 64);
            v.y += __shfl_down(v.y, off, 64);
            v.z += __shfl_down(v.z, off, 64);
            v.w += __shfl_down(v.w, off, 64);
        }
        if (tid == 0) {
            const float inv = 1.0f / (float)NPIX;
            float l0 = v.x * inv + bsel[0];
            float l1 = v.y * inv + bsel[1];
            float l2 = v.z * inv + bsel[2];
            float l3 = v.w * inv + bsel[3];
            float m  = fmaxf(fmaxf(l0, l1), fmaxf(l2, l3));
            float e0 = expf(l0 - m), e1 = expf(l1 - m);
            float e2 = expf(l2 - m), e3 = expf(l3 - m);
            float is = 1.0f / (e0 + e1 + e2 + e3);
            wts_s[0] = e0 * is; wts_s[1] = e1 * is;
            wts_s[2] = e2 * is; wts_s[3] = e3 * is;
        }
    }
    __syncthreads();
    float s0 = wts_s[0], s1 = wts_s[1], s2 = wts_s[2], s3 = wts_s[3];

    // out[p_k] = s0*x[p_k] + s1*x[p_{k+1}] + s2*x[p_{k+2}] + s3*x[p_{k+3}]
    nt_store4(&ob[p0], comb(s0, s1, s2, s3, a0, a1, a2, a3));
    nt_store4(&ob[p1], comb(s0, s1, s2, s3, a1, a2, a3, a0));
    nt_store4(&ob[p2], comb(s0, s1, s2, s3, a2, a3, a0, a1));
    nt_store4(&ob[p3], comb(s0, s1, s2, s3, a3, a0, a1, a2));
}

extern "C" void kernel_launch(void* const* d_in, const int* in_sizes, int n_in,
                              void* d_out, int out_size, void* d_ws, size_t ws_size,
                              hipStream_t stream) {
    const float* x    = (const float*)d_in[0];
    const float* Wsel = (const float*)d_in[1];
    const float* bsel = (const float*)d_in[2];
    float* out = (float*)d_out;

    float* partial = (float*)d_ws;   // 2048*4 floats

    k1_partial<<<BDIM * SLABS, 256, 0, stream>>>(x, Wsel, partial);
    k3_rot<<<BDIM * 512, 256, 0, stream>>>(x, partial, bsel, out);
}